// Round 2
// baseline (75.040 us; speedup 1.0000x reference)
//
#include <hip/hip_runtime.h>
#include <hip/hip_bf16.h>

typedef __attribute__((ext_vector_type(8))) short bf16x8;   // MFMA A/B frag (8 bf16)
typedef __attribute__((ext_vector_type(4))) float f32x4;    // MFMA C/D frag / float4
typedef __attribute__((ext_vector_type(4))) short s16x4;

#define LDSS 72    // staging row stride in bf16 elems (64 + 8 pad)
#define EST  260   // epilogue transpose-buffer row stride in f32 elems (256 + 4 pad -> 2-way alias on writes)

__device__ __forceinline__ short f2bf(float f) {
    union { float f; unsigned u; } v; v.f = f;
    unsigned r = v.u + 0x7fffu + ((v.u >> 16) & 1u);  // round-to-nearest-even
    return (short)(r >> 16);
}

// out[b,i,j] = ||x_i||^2 + ||y_j||^2 - 2 * dot(x_i, y_j)
// 64(i) x 256(j) tile per block. Swapped-operand MFMA => lane's 4 acc regs span
// consecutive j => float4 epilogue. LDS transpose => 1KB-contiguous dwordx4 stores.
__global__ __launch_bounds__(256) void pdist_kernel(
    const float* __restrict__ x, const float* __restrict__ y,
    float* __restrict__ out, int n)
{
    __shared__ union {
        short stage[(64 + 256) * LDSS];   // x rows [0,64), y rows [64,320)
        float ep[32 * EST];               // epilogue chunk: 32 rows x 256 cols
    } u;
    __shared__ float xn[64];
    __shared__ float yn[256];

    const int b  = blockIdx.z;
    const int i0 = blockIdx.y * 64;
    const int j0 = blockIdx.x * 256;
    const float* xb = x + ((size_t)b * n + i0) * 64;
    const float* yb = y + ((size_t)b * n + j0) * 64;
    const int t = threadIdx.x;

    // ---- stage y (1 row/thread): bf16 to LDS + fp32 norm ----
    {
        const f32x4* p = (const f32x4*)yb + (size_t)t * 16;
        float s = 0.f;
        #pragma unroll
        for (int c = 0; c < 16; ++c) {
            f32x4 v = p[c];
            s += v.x * v.x + v.y * v.y + v.z * v.z + v.w * v.w;
            s16x4 sv = { f2bf(v.x), f2bf(v.y), f2bf(v.z), f2bf(v.w) };
            *(s16x4*)&u.stage[(64 + t) * LDSS + c * 4] = sv;
        }
        yn[t] = s;
    }
    // ---- stage x (threads 0..63, 1 row/thread) ----
    if (t < 64) {
        const f32x4* p = (const f32x4*)xb + (size_t)t * 16;
        float s = 0.f;
        #pragma unroll
        for (int c = 0; c < 16; ++c) {
            f32x4 v = p[c];
            s += v.x * v.x + v.y * v.y + v.z * v.z + v.w * v.w;
            s16x4 sv = { f2bf(v.x), f2bf(v.y), f2bf(v.z), f2bf(v.w) };
            *(s16x4*)&u.stage[t * LDSS + c * 4] = sv;
        }
        xn[t] = s;
    }
    __syncthreads();

    // ---- fragment loads: wave w owns i in [0,64), j in [w*64, w*64+64) ----
    const int lane = t & 63;
    const int w    = t >> 6;
    const int lrow = lane & 15;
    const int quad = lane >> 4;

    const short* xbase = &u.stage[lrow * LDSS + quad * 8];
    const short* ybase = &u.stage[(64 + w * 64 + lrow) * LDSS + quad * 8];

    bf16x8 ax[4][2], by[4][2];
    #pragma unroll
    for (int ti = 0; ti < 4; ++ti) {
        ax[ti][0] = *(const bf16x8*)(xbase + ti * 16 * LDSS);
        ax[ti][1] = *(const bf16x8*)(xbase + ti * 16 * LDSS + 32);
        by[ti][0] = *(const bf16x8*)(ybase + ti * 16 * LDSS);
        by[ti][1] = *(const bf16x8*)(ybase + ti * 16 * LDSS + 32);
    }

    // ---- MFMA, swapped operands: first operand (y) row -> quad*4+reg (j),
    // second operand (x) row -> lane&15 (i). [verified by R1 passing kernel] ----
    f32x4 acc[4][4];   // [ti][tj]
    #pragma unroll
    for (int ti = 0; ti < 4; ++ti)
        #pragma unroll
        for (int tj = 0; tj < 4; ++tj) {
            f32x4 z = {0.f, 0.f, 0.f, 0.f};
            z = __builtin_amdgcn_mfma_f32_16x16x32_bf16(by[tj][0], ax[ti][0], z, 0, 0, 0);
            z = __builtin_amdgcn_mfma_f32_16x16x32_bf16(by[tj][1], ax[ti][1], z, 0, 0, 0);
            acc[ti][tj] = z;
        }

    // ---- epilogue: two 32-row chunks through LDS transpose, coalesced stores ----
    float* outb = out + (size_t)b * n * n;
    #pragma unroll
    for (int c = 0; c < 2; ++c) {
        __syncthreads();   // staging reads (c=0) / previous chunk readback (c=1) done
        #pragma unroll
        for (int tt = 0; tt < 2; ++tt) {
            const int ti = c * 2 + tt;
            const float xv = xn[ti * 16 + lrow];
            #pragma unroll
            for (int tj = 0; tj < 4; ++tj) {
                const int jb = w * 64 + tj * 16 + quad * 4;   // local j of reg 0
                f32x4 yv = *(const f32x4*)&yn[jb];
                f32x4 a  = acc[ti][tj];
                f32x4 v  = { xv + yv.x - 2.0f * a.x,
                             xv + yv.y - 2.0f * a.y,
                             xv + yv.z - 2.0f * a.z,
                             xv + yv.w - 2.0f * a.w };
                *(f32x4*)&u.ep[(tt * 16 + lrow) * EST + jb] = v;
            }
        }
        __syncthreads();
        // readback row-major: each wave instr covers one full 1KB row of the tile
        #pragma unroll
        for (int it = 0; it < 8; ++it) {
            const int idx  = t + it * 256;
            const int row  = idx >> 6;            // 64 float4 per 256-col row
            const int col4 = (idx & 63) << 2;
            f32x4 v = *(const f32x4*)&u.ep[row * EST + col4];
            *(f32x4*)&outb[(size_t)(i0 + c * 32 + row) * n + (j0 + col4)] = v;
        }
    }
}

extern "C" void kernel_launch(void* const* d_in, const int* in_sizes, int n_in,
                              void* d_out, int out_size, void* d_ws, size_t ws_size,
                              hipStream_t stream) {
    const float* x = (const float*)d_in[0];
    const float* y = (const float*)d_in[1];
    float* out = (float*)d_out;

    // in_sizes[0] = B*n*64, out_size = B*n*n  =>  n = out_size*64 / in_sizes[0]
    const long long n = ((long long)out_size * 64) / in_sizes[0];
    const long long B = (long long)in_sizes[0] / (n * 64);

    dim3 grid((unsigned)(n / 256), (unsigned)(n / 64), (unsigned)B);
    pdist_kernel<<<grid, 256, 0, stream>>>(x, y, out, (int)n);
}

// Round 3
// 74.748 us; speedup vs baseline: 1.0039x; 1.0039x over previous
//
#include <hip/hip_runtime.h>
#include <hip/hip_bf16.h>

typedef __attribute__((ext_vector_type(8))) short bf16x8;   // MFMA A/B frag (8 bf16)
typedef __attribute__((ext_vector_type(4))) float f32x4;    // MFMA C/D frag / float4

__device__ __forceinline__ short f2bf(float f) {
    union { float f; unsigned u; } v; v.f = f;
    unsigned r = v.u + 0x7fffu + ((v.u >> 16) & 1u);  // round-to-nearest-even
    return (short)(r >> 16);
}

// out[b,i,j] = ||x_i||^2 + ||y_j||^2 - 2 * dot(x_i, y_j)
// LDS-free, barrier-free. 64(i) x 256(j) tile per block, wave w owns j-quadrant.
// Fragments loaded straight from global (row-major [row][k] IS the MFMA
// A-operand layout: row=lane&15, k=quad*8+j). Norms via shfl_xor butterfly
// from the same registers. Swapped-operand MFMA => acc regs span consecutive j
// => direct float4 stores (16x 256B segments per wave instr).
__global__ __launch_bounds__(256) void pdist_kernel(
    const float* __restrict__ x, const float* __restrict__ y,
    float* __restrict__ out, int n)
{
    const int b    = blockIdx.z;
    const int i0   = blockIdx.y * 64;
    const int j0   = blockIdx.x * 256;
    const int t    = threadIdx.x;
    const int lane = t & 63;
    const int w    = t >> 6;
    const int lrow = lane & 15;
    const int quad = lane >> 4;

    const float* xb = x + ((size_t)b * n + i0) * 64;
    const float* yb = y + ((size_t)b * n + j0 + w * 64) * 64;

    // ---- x fragments: rows ti*16+lrow, k halves {quad*8, 32+quad*8} ----
    bf16x8 ax[4][2]; float xnrm[4];
    #pragma unroll
    for (int ti = 0; ti < 4; ++ti) {
        const float* p = xb + (size_t)(ti * 16 + lrow) * 64 + quad * 8;
        f32x4 v0 = *(const f32x4*)p;
        f32x4 v1 = *(const f32x4*)(p + 4);
        f32x4 v2 = *(const f32x4*)(p + 32);
        f32x4 v3 = *(const f32x4*)(p + 36);
        float s = v0.x*v0.x + v0.y*v0.y + v0.z*v0.z + v0.w*v0.w
                + v1.x*v1.x + v1.y*v1.y + v1.z*v1.z + v1.w*v1.w
                + v2.x*v2.x + v2.y*v2.y + v2.z*v2.z + v2.w*v2.w
                + v3.x*v3.x + v3.y*v3.y + v3.z*v3.z + v3.w*v3.w;
        s += __shfl_xor(s, 16);
        s += __shfl_xor(s, 32);           // norm of row ti*16+lrow, replicated over quads
        xnrm[ti] = s;
        bf16x8 f0 = { f2bf(v0.x), f2bf(v0.y), f2bf(v0.z), f2bf(v0.w),
                      f2bf(v1.x), f2bf(v1.y), f2bf(v1.z), f2bf(v1.w) };
        bf16x8 f1 = { f2bf(v2.x), f2bf(v2.y), f2bf(v2.z), f2bf(v2.w),
                      f2bf(v3.x), f2bf(v3.y), f2bf(v3.z), f2bf(v3.w) };
        ax[ti][0] = f0; ax[ti][1] = f1;
    }

    // ---- y fragments: rows tj*16+lrow (within wave's 64-row j strip) ----
    bf16x8 by[4][2]; float ynrm[4];
    #pragma unroll
    for (int tj = 0; tj < 4; ++tj) {
        const float* p = yb + (size_t)(tj * 16 + lrow) * 64 + quad * 8;
        f32x4 v0 = *(const f32x4*)p;
        f32x4 v1 = *(const f32x4*)(p + 4);
        f32x4 v2 = *(const f32x4*)(p + 32);
        f32x4 v3 = *(const f32x4*)(p + 36);
        float s = v0.x*v0.x + v0.y*v0.y + v0.z*v0.z + v0.w*v0.w
                + v1.x*v1.x + v1.y*v1.y + v1.z*v1.z + v1.w*v1.w
                + v2.x*v2.x + v2.y*v2.y + v2.z*v2.z + v2.w*v2.w
                + v3.x*v3.x + v3.y*v3.y + v3.z*v3.z + v3.w*v3.w;
        s += __shfl_xor(s, 16);
        s += __shfl_xor(s, 32);           // norm of y row tj*16+lrow, replicated over quads
        ynrm[tj] = s;
        bf16x8 f0 = { f2bf(v0.x), f2bf(v0.y), f2bf(v0.z), f2bf(v0.w),
                      f2bf(v1.x), f2bf(v1.y), f2bf(v1.z), f2bf(v1.w) };
        bf16x8 f1 = { f2bf(v2.x), f2bf(v2.y), f2bf(v2.z), f2bf(v2.w),
                      f2bf(v3.x), f2bf(v3.y), f2bf(v3.z), f2bf(v3.w) };
        by[tj][0] = f0; by[tj][1] = f1;
    }

    // ---- MFMA, swapped operands: first operand (y) row -> quad*4+reg (j),
    // second operand (x) row -> lane&15 (i). [verified by R1/R2 passing] ----
    f32x4 acc[4][4];
    #pragma unroll
    for (int ti = 0; ti < 4; ++ti)
        #pragma unroll
        for (int tj = 0; tj < 4; ++tj) {
            f32x4 z = {0.f, 0.f, 0.f, 0.f};
            z = __builtin_amdgcn_mfma_f32_16x16x32_bf16(by[tj][0], ax[ti][0], z, 0, 0, 0);
            z = __builtin_amdgcn_mfma_f32_16x16x32_bf16(by[tj][1], ax[ti][1], z, 0, 0, 0);
            acc[ti][tj] = z;
        }

    // ---- epilogue: gather y norms for j = tj*16 + quad*4 + r via bpermute,
    // combine, direct float4 stores ----
    float* outb = out + (size_t)b * n * n;
    #pragma unroll
    for (int tj = 0; tj < 4; ++tj) {
        f32x4 yv;
        yv.x = __shfl(ynrm[tj], quad * 4 + 0);
        yv.y = __shfl(ynrm[tj], quad * 4 + 1);
        yv.z = __shfl(ynrm[tj], quad * 4 + 2);
        yv.w = __shfl(ynrm[tj], quad * 4 + 3);
        const int gj = j0 + w * 64 + tj * 16 + quad * 4;
        #pragma unroll
        for (int ti = 0; ti < 4; ++ti) {
            const int gi = i0 + ti * 16 + lrow;
            f32x4 a = acc[ti][tj];
            f32x4 v = { xnrm[ti] + yv.x - 2.0f * a.x,
                        xnrm[ti] + yv.y - 2.0f * a.y,
                        xnrm[ti] + yv.z - 2.0f * a.z,
                        xnrm[ti] + yv.w - 2.0f * a.w };
            *(f32x4*)&outb[(size_t)gi * n + gj] = v;
        }
    }
}

extern "C" void kernel_launch(void* const* d_in, const int* in_sizes, int n_in,
                              void* d_out, int out_size, void* d_ws, size_t ws_size,
                              hipStream_t stream) {
    const float* x = (const float*)d_in[0];
    const float* y = (const float*)d_in[1];
    float* out = (float*)d_out;

    // in_sizes[0] = B*n*64, out_size = B*n*n  =>  n = out_size*64 / in_sizes[0]
    const long long n = ((long long)out_size * 64) / in_sizes[0];
    const long long B = (long long)in_sizes[0] / (n * 64);

    dim3 grid((unsigned)(n / 256), (unsigned)(n / 64), (unsigned)B);
    pdist_kernel<<<grid, 256, 0, stream>>>(x, y, out, (int)n);
}